// Round 1
// baseline (37858.279 us; speedup 1.0000x reference)
//
#include <hip/hip_runtime.h>
#include <cstdint>
#include <cstddef>

#define NBLK 256
#define NTHR 512
#define B_ 64
#define P_ 196
#define E_ 512
#define A_ 512
#define D_ 512
#define M_ 512
#define V_ 1000
#define L_ 257
#define T_ 256

#define OUT_PRED  0
#define OUT_CAPS  (B_*T_*V_)                 /* 16,384,000 */
#define OUT_ALPHA (OUT_CAPS + B_*L_)         /* 16,400,448 */
#define OUT_SORT  (OUT_ALPHA + B_*T_*P_)     /* 19,611,712 */

struct KP {
  const float* enc; const int* caps; const int* clen;
  const float* emb;
  const float* eaw; const float* eab;
  const float* daw; const float* dab;
  const float* faw; const float* fab;
  const float* wih; const float* bih;
  const float* whh; const float* bhh;
  const float* ihw; const float* ihb;
  const float* icw; const float* icb;
  const float* fbw; const float* fbb;
  const float* fcw; const float* fcb;
  float* out;
  int* bar;
  int* sort_ind; int* dec_len; int* capT;
  float* hb0; float* hb1; float* cT; float* hnT;
  float* a2T; float* gsT; float* xT; float* mnT; float* att1;
};

__device__ __forceinline__ float dot4(float4 a, float4 b){
  return a.x*b.x + a.y*b.y + a.z*b.z + a.w*b.w;
}
__device__ __forceinline__ float sigf(float x){ return 1.f/(1.f+__expf(-x)); }
__device__ __forceinline__ float tanhf_(float x){
  float ax = fabsf(x);
  float e = __expf(-2.f*ax);
  float r = (1.f-e)/(1.f+e);
  return x < 0.f ? -r : r;
}

// Sense-reversing grid barrier. Relaxed spin + one acquire fence on exit so the
// spinning CUs don't hammer L2 invalidates every poll.
__device__ __forceinline__ void gridbar(int* bar){
  __syncthreads();
  if (threadIdx.x == 0){
    __builtin_amdgcn_fence(__ATOMIC_RELEASE, "agent");
    int s = __hip_atomic_load(&bar[1], __ATOMIC_RELAXED, __HIP_MEMORY_SCOPE_AGENT);
    int prev = __hip_atomic_fetch_add(&bar[0], 1, __ATOMIC_RELAXED, __HIP_MEMORY_SCOPE_AGENT);
    if (prev == NBLK-1){
      __hip_atomic_store(&bar[0], 0, __ATOMIC_RELAXED, __HIP_MEMORY_SCOPE_AGENT);
      __hip_atomic_store(&bar[1], s+1, __ATOMIC_RELEASE, __HIP_MEMORY_SCOPE_AGENT);
    } else {
      while (__hip_atomic_load(&bar[1], __ATOMIC_RELAXED, __HIP_MEMORY_SCOPE_AGENT) == s){
        __builtin_amdgcn_s_sleep(1);
      }
    }
    __builtin_amdgcn_fence(__ATOMIC_ACQUIRE, "agent");
  }
  __syncthreads();
}

// smem: max(att1 tile: 512*33 + 64*33 = 19008 floats = 74.25 KB)
__global__ __launch_bounds__(NTHR, 2) void dec_kernel(KP p){
  __shared__ __align__(16) float smem[19008];
  const int blk  = blockIdx.x;
  const int tid  = threadIdx.x;
  const int lane = tid & 63;
  const int wave = tid >> 6;
  const int gw   = blk*8 + wave;      // 0..2047

  // ---------------- Pre0: stable descending argsort + caps gather ----------------
  if (blk == 0){
    if (tid < B_){
      int lb = p.clen[tid];
      int rank = 0;
      for (int j = 0; j < B_; j++){
        int lj = p.clen[j];
        rank += (lj > lb) || (lj == lb && j < tid);
      }
      p.sort_ind[rank] = tid;
      p.dec_len[rank]  = lb - 1;
      p.out[OUT_SORT + rank] = (float)tid;
    }
    __syncthreads();
    for (int idx = tid; idx < B_*L_; idx += NTHR){
      int b = idx / L_;
      int l = idx - b*L_;
      int sb = p.sort_ind[b];
      int cv = p.caps[sb*L_ + l];
      p.out[OUT_CAPS + idx] = (float)cv;
      p.capT[l*B_ + b] = cv;
    }
  }
  gridbar(p.bar);

  // ---------------- Pre1: att1 = enc_s @ enc_att_w^T + b  (196 tiles) + mean (64) ----------------
  for (int task = blk; task < 260; task += NBLK){
    if (task < 196){
      const int r0 = task*64;
      float* wL = smem;             // [512][33]
      float* eL = smem + 512*33;    // [64][33]
      const int tx = tid & 31, ty = tid >> 5;   // ty<16
      float acc[4][16];
      #pragma unroll
      for (int i=0;i<4;i++)
        #pragma unroll
        for (int j=0;j<16;j++) acc[i][j] = 0.f;
      for (int k0 = 0; k0 < 512; k0 += 32){
        __syncthreads();
        for (int i = tid; i < 512*32; i += NTHR){
          int a = i >> 5, kk = i & 31;
          wL[a*33 + kk] = p.eaw[a*512 + k0 + kk];
        }
        for (int i = tid; i < 64*32; i += NTHR){
          int rl = i >> 5, kk = i & 31;
          int r = r0 + rl;
          int b = r / 196;
          int pp = r - b*196;
          int sb = p.sort_ind[b];
          eL[rl*33 + kk] = p.enc[((size_t)sb*196 + pp)*512 + k0 + kk];
        }
        __syncthreads();
        for (int kk = 0; kk < 32; kk++){
          float ev[4];
          #pragma unroll
          for (int ii=0;ii<4;ii++) ev[ii] = eL[(ty*4+ii)*33 + kk];
          #pragma unroll
          for (int jj=0;jj<16;jj++){
            float wv = wL[(tx + 32*jj)*33 + kk];
            #pragma unroll
            for (int ii=0;ii<4;ii++) acc[ii][jj] = fmaf(ev[ii], wv, acc[ii][jj]);
          }
        }
      }
      #pragma unroll
      for (int jj=0;jj<16;jj++){
        int a = tx + 32*jj;
        float bb = p.eab[a];
        #pragma unroll
        for (int ii=0;ii<4;ii++){
          int r = r0 + ty*4 + ii;
          p.att1[(size_t)r*512 + a] = acc[ii][jj] + bb;
        }
      }
      __syncthreads();
    } else {
      int b = task - 196;
      int sb = p.sort_ind[b];
      const float* eb = p.enc + (size_t)sb*P_*E_;
      for (int e = tid; e < E_; e += NTHR){
        float s = 0.f;
        for (int pp = 0; pp < P_; pp++) s += eb[pp*E_ + e];
        s *= (1.f/196.f);
        p.mnT[((e>>2)*64 + b)*4 + (e&3)] = s;
      }
    }
  }
  gridbar(p.bar);

  // ---------------- Pre2: h0 / c0 ----------------
  for (int wt = gw; wt < 1024; wt += 2048){
    const int j = wt & 511;
    const bool isC = wt >= 512;
    const float4* x4 = (const float4*)p.mnT;
    const float4* w4 = (const float4*)((isC ? p.icw : p.ihw) + (size_t)j*E_);
    float acc = 0.f;
    #pragma unroll 4
    for (int k4 = 0; k4 < 128; k4++) acc += dot4(x4[k4*64 + lane], w4[k4]);
    acc += (isC ? p.icb : p.ihb)[j];
    if (isC) p.cT[j*64 + lane] = acc;
    else     p.hb0[((j>>2)*64 + lane)*4 + (j&3)] = acc;
  }
  gridbar(p.bar);

  // ---------------- time loop ----------------
  for (int t = 0; t < T_; t++){
    const float* hT = (t & 1) ? p.hb1 : p.hb0;
    float*       hN = (t & 1) ? p.hb0 : p.hb1;

    // ---- P1: att2 (512) | gate (512) | emb gather (128) | preds(t-1) (1000) ----
    for (int wt = gw; wt < 2152; wt += 2048){
      if (wt < 512){
        const int a = wt;
        const float4* h4 = (const float4*)hT;
        const float4* w4 = (const float4*)(p.daw + (size_t)a*D_);
        float acc = 0.f;
        #pragma unroll 4
        for (int k4 = 0; k4 < 128; k4++) acc += dot4(h4[k4*64+lane], w4[k4]);
        acc += p.dab[a];
        p.a2T[((a>>2)*64 + lane)*4 + (a&3)] = acc;
      } else if (wt < 1024){
        const int e = wt - 512;
        const float4* h4 = (const float4*)hT;
        const float4* w4 = (const float4*)(p.fbw + (size_t)e*D_);
        float acc = 0.f;
        #pragma unroll 4
        for (int k4 = 0; k4 < 128; k4++) acc += dot4(h4[k4*64+lane], w4[k4]);
        acc = sigf(acc + p.fbb[e]);
        p.gsT[((e>>2)*64 + lane)*4 + (e&3)] = acc;
      } else if (wt < 1152){
        const int k4 = wt - 1024;
        int cap = p.capT[t*B_ + lane];
        float4 ev = *(const float4*)(p.emb + (size_t)cap*M_ + k4*4);
        ((float4*)p.xT)[k4*64 + lane] = ev;
      } else {
        if (t > 0){
          const int v = wt - 1152;
          const float4* h4 = (const float4*)p.hnT;
          const float4* w4 = (const float4*)(p.fcw + (size_t)v*D_);
          float acc = 0.f;
          #pragma unroll 4
          for (int k4 = 0; k4 < 128; k4++) acc += dot4(h4[k4*64+lane], w4[k4]);
          acc += p.fcb[v];
          bool m = (t-1) < p.dec_len[lane];
          p.out[OUT_PRED + ((size_t)lane*T_ + (t-1))*V_ + v] = m ? acc : 0.f;
        }
      }
    }
    gridbar(p.bar);

    // ---- P2: attention (block-per-b): e -> softmax -> awe, write alphas ----
    if (blk < B_){
      const int b = blk;
      const int sb = p.sort_ind[b];
      float* a2L = smem;          // 512
      float* fwL = smem + 512;    // 512
      float* eLd = smem + 1024;   // 196
      float* alL = smem + 1224;   // 196
      a2L[tid < 512 ? tid : 0] = a2L[0]; // no-op guard removed below; real staging:
      {
        int i = tid;
        a2L[i] = p.a2T[((i>>2)*64 + b)*4 + (i&3)];
        fwL[i] = p.faw[i];
      }
      __syncthreads();
      for (int pp = wave; pp < P_; pp += 8){
        const float4* ar = (const float4*)(p.att1 + ((size_t)b*P_ + pp)*A_);
        float acc = 0.f;
        #pragma unroll
        for (int q = 0; q < 2; q++){
          int i4 = q*64 + lane;
          float4 av = ar[i4];
          float4 t2 = *(const float4*)&a2L[i4*4];
          float4 fw = *(const float4*)&fwL[i4*4];
          acc += fmaxf(av.x + t2.x, 0.f)*fw.x;
          acc += fmaxf(av.y + t2.y, 0.f)*fw.y;
          acc += fmaxf(av.z + t2.z, 0.f)*fw.z;
          acc += fmaxf(av.w + t2.w, 0.f)*fw.w;
        }
        #pragma unroll
        for (int o = 32; o > 0; o >>= 1) acc += __shfl_down(acc, o);
        if (lane == 0) eLd[pp] = acc + p.fab[0];
      }
      __syncthreads();
      if (wave == 0){
        float mx = -1e30f;
        for (int i = lane; i < P_; i += 64) mx = fmaxf(mx, eLd[i]);
        #pragma unroll
        for (int o = 32; o > 0; o >>= 1) mx = fmaxf(mx, __shfl_xor(mx, o));
        float sum = 0.f;
        for (int i = lane; i < P_; i += 64){
          float ex = __expf(eLd[i] - mx);
          alL[i] = ex;
          sum += ex;
        }
        #pragma unroll
        for (int o = 32; o > 0; o >>= 1) sum += __shfl_xor(sum, o);
        float inv = 1.f / sum;
        for (int i = lane; i < P_; i += 64) alL[i] *= inv;
      }
      __syncthreads();
      const bool m = t < p.dec_len[b];
      for (int i = tid; i < P_; i += NTHR){
        p.out[OUT_ALPHA + ((size_t)b*T_ + t)*P_ + i] = m ? alL[i] : 0.f;
      }
      {
        const int e = tid;
        const float* eb = p.enc + (size_t)sb*P_*E_;
        float s0=0.f,s1=0.f,s2=0.f,s3=0.f;
        for (int pp = 0; pp < P_; pp += 4){
          s0 = fmaf(eb[(pp+0)*E_ + e], alL[pp+0], s0);
          s1 = fmaf(eb[(pp+1)*E_ + e], alL[pp+1], s1);
          s2 = fmaf(eb[(pp+2)*E_ + e], alL[pp+2], s2);
          s3 = fmaf(eb[(pp+3)*E_ + e], alL[pp+3], s3);
        }
        float aw = (s0+s1)+(s2+s3);
        float g = p.gsT[((e>>2)*64 + b)*4 + (e&3)];
        int k = 512 + e;
        p.xT[((k>>2)*64 + b)*4 + (k&3)] = g * aw;
      }
    }
    gridbar(p.bar);

    // ---- P3: gates GEMM (K-split 4 waves) + LSTM pointwise; block owns 2 j ----
    {
      const int j  = blk*2 + (wave >> 2);
      const int kc = wave & 3;
      float ag[4] = {0.f,0.f,0.f,0.f};
      const float4* x4 = (const float4*)p.xT;
      const float4* h4 = (const float4*)hT;
      for (int kk = 0; kk < 384; kk += 4){
        int k = kc*384 + kk;
        if (k < 1024){
          float4 xv = x4[(k>>2)*64 + lane];
          #pragma unroll
          for (int g = 0; g < 4; g++){
            float4 wv = *(const float4*)(p.wih + (size_t)(j + 512*g)*1024 + k);
            ag[g] = fmaf(xv.x, wv.x, ag[g]); ag[g] = fmaf(xv.y, wv.y, ag[g]);
            ag[g] = fmaf(xv.z, wv.z, ag[g]); ag[g] = fmaf(xv.w, wv.w, ag[g]);
          }
        } else {
          int kh = k - 1024;
          float4 xv = h4[(kh>>2)*64 + lane];
          #pragma unroll
          for (int g = 0; g < 4; g++){
            float4 wv = *(const float4*)(p.whh + (size_t)(j + 512*g)*512 + kh);
            ag[g] = fmaf(xv.x, wv.x, ag[g]); ag[g] = fmaf(xv.y, wv.y, ag[g]);
            ag[g] = fmaf(xv.z, wv.z, ag[g]); ag[g] = fmaf(xv.w, wv.w, ag[g]);
          }
        }
      }
      float (*part)[4][64] = (float (*)[4][64])smem;
      #pragma unroll
      for (int g = 0; g < 4; g++) part[wave][g][lane] = ag[g];
      __syncthreads();
      if ((wave & 3) == 0){
        const int wb = wave;
        float gs[4];
        #pragma unroll
        for (int g = 0; g < 4; g++){
          gs[g] = part[wb][g][lane] + part[wb+1][g][lane] + part[wb+2][g][lane] + part[wb+3][g][lane]
                + p.bih[j + 512*g] + p.bhh[j + 512*g];
        }
        float c_old = p.cT[j*64 + lane];
        float i_s = sigf(gs[0]);
        float f_s = sigf(gs[1]);
        float g_t = tanhf_(gs[2]);
        float o_s = sigf(gs[3]);
        float c_new = f_s*c_old + i_s*g_t;
        float h_new = o_s*tanhf_(c_new);
        bool m = t < p.dec_len[lane];
        float h_old = hT[((j>>2)*64 + lane)*4 + (j&3)];
        float h2 = m ? h_new : h_old;
        float c2 = m ? c_new : c_old;
        p.cT[j*64 + lane] = c2;
        p.hnT[((j>>2)*64 + lane)*4 + (j&3)] = h_new;
        hN  [((j>>2)*64 + lane)*4 + (j&3)] = h2;
      }
    }
    gridbar(p.bar);
  }

  // ---- final preds for t = T-1 ----
  for (int wt = gw; wt < 1000; wt += 2048){
    const int v = wt;
    const float4* h4 = (const float4*)p.hnT;
    const float4* w4 = (const float4*)(p.fcw + (size_t)v*D_);
    float acc = 0.f;
    #pragma unroll 4
    for (int k4 = 0; k4 < 128; k4++) acc += dot4(h4[k4*64+lane], w4[k4]);
    acc += p.fcb[v];
    bool m = (T_-1) < p.dec_len[lane];
    p.out[OUT_PRED + ((size_t)lane*T_ + (T_-1))*V_ + v] = m ? acc : 0.f;
  }
}

extern "C" void kernel_launch(void* const* d_in, const int* in_sizes, int n_in,
                              void* d_out, int out_size, void* d_ws, size_t ws_size,
                              hipStream_t stream){
  (void)in_sizes; (void)n_in; (void)out_size; (void)ws_size;
  KP p;
  p.enc  = (const float*)d_in[0];
  p.caps = (const int*)  d_in[1];
  p.clen = (const int*)  d_in[2];
  p.emb  = (const float*)d_in[3];
  p.eaw  = (const float*)d_in[4];  p.eab = (const float*)d_in[5];
  p.daw  = (const float*)d_in[6];  p.dab = (const float*)d_in[7];
  p.faw  = (const float*)d_in[8];  p.fab = (const float*)d_in[9];
  p.wih  = (const float*)d_in[10]; p.bih = (const float*)d_in[11];
  p.whh  = (const float*)d_in[12]; p.bhh = (const float*)d_in[13];
  p.ihw  = (const float*)d_in[14]; p.ihb = (const float*)d_in[15];
  p.icw  = (const float*)d_in[16]; p.icb = (const float*)d_in[17];
  p.fbw  = (const float*)d_in[18]; p.fbb = (const float*)d_in[19];
  p.fcw  = (const float*)d_in[20]; p.fcb = (const float*)d_in[21];
  p.out  = (float*)d_out;

  char* ws = (char*)d_ws;
  size_t off = 0;
  p.bar      = (int*)(ws + off); off += 256;
  p.sort_ind = (int*)(ws + off); off += 64*4;
  p.dec_len  = (int*)(ws + off); off += 64*4;
  p.capT     = (int*)(ws + off); off += (size_t)L_*B_*4;
  off = (off + 255) & ~(size_t)255;
  p.hb0 = (float*)(ws + off); off += (size_t)D_*B_*4;
  p.hb1 = (float*)(ws + off); off += (size_t)D_*B_*4;
  p.cT  = (float*)(ws + off); off += (size_t)D_*B_*4;
  p.hnT = (float*)(ws + off); off += (size_t)D_*B_*4;
  p.a2T = (float*)(ws + off); off += (size_t)A_*B_*4;
  p.gsT = (float*)(ws + off); off += (size_t)E_*B_*4;
  p.xT  = (float*)(ws + off); off += (size_t)(M_+E_)*B_*4;
  p.mnT = (float*)(ws + off); off += (size_t)E_*B_*4;
  p.att1= (float*)(ws + off); off += (size_t)B_*P_*A_*4;

  hipMemsetAsync(p.bar, 0, 256, stream);
  dec_kernel<<<dim3(NBLK), dim3(NTHR), 0, stream>>>(p);
}

// Round 3
// 24460.077 us; speedup vs baseline: 1.5478x; 1.5478x over previous
//
#include <hip/hip_runtime.h>
#include <cstdint>
#include <cstddef>

#define NBLK 256
#define NTHR 512
#define B_ 64
#define P_ 196
#define E_ 512
#define A_ 512
#define D_ 512
#define M_ 512
#define V_ 1000
#define L_ 257
#define T_ 256

#define OUT_PRED  0
#define OUT_CAPS  (B_*T_*V_)                 /* 16,384,000 */
#define OUT_ALPHA (OUT_CAPS + B_*L_)         /* 16,400,448 */
#define OUT_SORT  (OUT_ALPHA + B_*T_*P_)     /* 19,611,712 */

struct KP {
  const float* enc; const int* caps; const int* clen;
  const float* emb;
  const float* eaw; const float* eab;
  const float* daw; const float* dab;
  const float* faw; const float* fab;
  const float* wih; const float* bih;
  const float* whh; const float* bhh;
  const float* ihw; const float* ihb;
  const float* icw; const float* icb;
  const float* fbw; const float* fbb;
  const float* fcw; const float* fcb;
  float* out;
  int* bar; int* gsync;
  int* sort_ind; int* dec_len; int* capT;
  float* hb0; float* hb1; float* cT; float* hnT;
  float* a2B; float* gateB; float* hB; float* xT; float* mnT; float* eG; float* att1;
};

__device__ __forceinline__ float dot4(float4 a, float4 b){
  return a.x*b.x + a.y*b.y + a.z*b.z + a.w*b.w;
}
__device__ __forceinline__ float sigf(float x){ return 1.f/(1.f+__expf(-x)); }
__device__ __forceinline__ float tanhf_(float x){
  float ax = fabsf(x);
  float e = __expf(-2.f*ax);
  float r = (1.f-e)/(1.f+e);
  return x < 0.f ? -r : r;
}
__device__ __forceinline__ unsigned short f2bf(float x){
  unsigned u = __float_as_uint(x);
  unsigned r = (u + 0x7fffu + ((u >> 16) & 1u)) >> 16;   // RNE
  return (unsigned short)r;
}
__device__ __forceinline__ float bf2f(unsigned short v){
  return __uint_as_float(((unsigned)v) << 16);
}

#define LD_A(p)     __hip_atomic_load((p), __ATOMIC_RELAXED, __HIP_MEMORY_SCOPE_AGENT)
#define ST_A(p,v)   __hip_atomic_store((p),(v), __ATOMIC_RELAXED, __HIP_MEMORY_SCOPE_AGENT)
#define ST_REL(p,v) __hip_atomic_store((p),(v), __ATOMIC_RELEASE, __HIP_MEMORY_SCOPE_AGENT)
#define FAA(p)      __hip_atomic_fetch_add((p),1, __ATOMIC_RELAXED, __HIP_MEMORY_SCOPE_AGENT)

// Grid barrier, 2-level tree: 8 leaf counters + root. Co-residency of all 256
// blocks is guaranteed by hipLaunchCooperativeKernel (launch fails loudly
// instead of deadlocking if the grid cannot be fully resident).
__device__ __forceinline__ void gridbar(int* bar, int blk){
  __syncthreads();
  if (threadIdx.x == 0){
    __builtin_amdgcn_fence(__ATOMIC_RELEASE, "agent");
    int s = LD_A(&bar[144]);
    int* leaf = &bar[(blk & 7)*16];
    if (FAA(leaf) == 31){
      ST_A(leaf, 0);
      if (FAA(&bar[128]) == 7){
        ST_A(&bar[128], 0);
        ST_REL(&bar[144], s+1);
      }
    }
    while (LD_A(&bar[144]) == s) __builtin_amdgcn_s_sleep(2);
    __builtin_amdgcn_fence(__ATOMIC_ACQUIRE, "agent");
  }
  __syncthreads();
}

// 4-block sub-barrier (one group = one batch row b).
__device__ __forceinline__ void groupbar(int* gs){
  __syncthreads();
  if (threadIdx.x == 0){
    __builtin_amdgcn_fence(__ATOMIC_RELEASE, "agent");
    int s = LD_A(&gs[1]);
    if (FAA(&gs[0]) == 3){
      ST_A(&gs[0], 0);
      ST_REL(&gs[1], s+1);
    } else {
      while (LD_A(&gs[1]) == s) __builtin_amdgcn_s_sleep(1);
    }
    __builtin_amdgcn_fence(__ATOMIC_ACQUIRE, "agent");
  }
  __syncthreads();
}

// LDS map (118,304 B total):
//   [0,      50176) att1L  bf16[49][512]   resident (written after Pre1)
//   [50176, 100352) encL   bf16[49][512]   resident
//   [100352,102400) fwL    f32[512]        resident
//   [102400,104448) hL     f32[512]        phase-A scratch
//   [104448,106496) a2L    f32[512]
//   [106496,107280) eL     f32[196]
//   [107280,108064) alL    f32[196]
//   [108064,110112) predP  f32[8][64]
//   [110112,118304) part   f32[8][4][64]   phase-C scratch
// Pre1 tile GEMM aliases [0, 76032) -- dead before residents are written.
__global__ __launch_bounds__(NTHR, 2) void dec_kernel(KP p){
  __shared__ __align__(16) char smem_raw[118304];
  unsigned short* att1L = (unsigned short*)smem_raw;
  unsigned short* encL  = (unsigned short*)(smem_raw + 50176);
  float* fwL   = (float*)(smem_raw + 100352);
  float* hL    = (float*)(smem_raw + 102400);
  float* a2L   = (float*)(smem_raw + 104448);
  float* eL    = (float*)(smem_raw + 106496);
  float* alL   = (float*)(smem_raw + 107280);
  float* predP = (float*)(smem_raw + 108064);
  float* part  = (float*)(smem_raw + 110112);

  const int blk  = blockIdx.x;
  const int tid  = threadIdx.x;
  const int lane = tid & 63;
  const int wave = tid >> 6;
  const int gw   = blk*8 + wave;      // 0..2047
  const int b    = blk >> 2;          // group's batch row
  const int q    = blk & 3;           // quadrant within group
  int* gs = &p.gsync[b*16];

  // ---------------- Pre0: stable descending argsort + caps gather ----------------
  if (blk == 0){
    if (tid < B_){
      int lb = p.clen[tid];
      int rank = 0;
      for (int j = 0; j < B_; j++){
        int lj = p.clen[j];
        rank += (lj > lb) || (lj == lb && j < tid);
      }
      p.sort_ind[rank] = tid;
      p.dec_len[rank]  = lb - 1;
      p.out[OUT_SORT + rank] = (float)tid;
    }
    __syncthreads();
    for (int idx = tid; idx < B_*L_; idx += NTHR){
      int bb = idx / L_;
      int l = idx - bb*L_;
      int sb = p.sort_ind[bb];
      int cv = p.caps[sb*L_ + l];
      p.out[OUT_CAPS + idx] = (float)cv;
      p.capT[l*B_ + bb] = cv;
    }
  }
  gridbar(p.bar, blk);

  // ---------------- Pre1: att1 = enc_s @ enc_att_w^T + b (196 tiles) + mean (64) ----------------
  for (int task = blk; task < 260; task += NBLK){
    if (task < 196){
      const int r0 = task*64;
      float* wL = (float*)smem_raw;             // [512][33]
      float* eLt = (float*)smem_raw + 512*33;   // [64][33]
      const int tx = tid & 31, ty = tid >> 5;   // ty<16
      float acc[4][16];
      #pragma unroll
      for (int i=0;i<4;i++)
        #pragma unroll
        for (int j=0;j<16;j++) acc[i][j] = 0.f;
      for (int k0 = 0; k0 < 512; k0 += 32){
        __syncthreads();
        for (int i = tid; i < 512*32; i += NTHR){
          int a = i >> 5, kk = i & 31;
          wL[a*33 + kk] = p.eaw[a*512 + k0 + kk];
        }
        for (int i = tid; i < 64*32; i += NTHR){
          int rl = i >> 5, kk = i & 31;
          int r = r0 + rl;
          int bb = r / 196;
          int pp = r - bb*196;
          int sb = p.sort_ind[bb];
          eLt[rl*33 + kk] = p.enc[((size_t)sb*196 + pp)*512 + k0 + kk];
        }
        __syncthreads();
        for (int kk = 0; kk < 32; kk++){
          float ev[4];
          #pragma unroll
          for (int ii=0;ii<4;ii++) ev[ii] = eLt[(ty*4+ii)*33 + kk];
          #pragma unroll
          for (int jj=0;jj<16;jj++){
            float wv = wL[(tx + 32*jj)*33 + kk];
            #pragma unroll
            for (int ii=0;ii<4;ii++) acc[ii][jj] = fmaf(ev[ii], wv, acc[ii][jj]);
          }
        }
      }
      #pragma unroll
      for (int jj=0;jj<16;jj++){
        int a = tx + 32*jj;
        float bbv = p.eab[a];
        #pragma unroll
        for (int ii=0;ii<4;ii++){
          int r = r0 + ty*4 + ii;
          p.att1[(size_t)r*512 + a] = acc[ii][jj] + bbv;
        }
      }
      __syncthreads();
    } else {
      int bb = task - 196;
      int sb = p.sort_ind[bb];
      const float* eb = p.enc + (size_t)sb*P_*E_;
      for (int e = tid; e < E_; e += NTHR){
        float s = 0.f;
        for (int pp = 0; pp < P_; pp++) s += eb[pp*E_ + e];
        s *= (1.f/196.f);
        p.mnT[((e>>2)*64 + bb)*4 + (e&3)] = s;
      }
    }
  }
  gridbar(p.bar, blk);

  // ---------------- Pre1.5: stage resident LDS (att1, enc -> bf16; fw) + Pre2: h0/c0 ----------------
  {
    const int sb = p.sort_ind[b];
    for (int idx = tid; idx < 49*512; idx += NTHR){
      int pp = idx >> 9, a = idx & 511;
      att1L[idx] = f2bf(p.att1[((size_t)(b*196 + q*49 + pp))*512 + a]);
      encL[idx]  = f2bf(p.enc[((size_t)sb*196 + q*49 + pp)*512 + a]);
    }
    fwL[tid] = p.faw[tid];
  }
  for (int wt = gw; wt < 1024; wt += 2048){
    const int j = wt & 511;
    const bool isC = wt >= 512;
    const float4* x4 = (const float4*)p.mnT;
    const float4* w4 = (const float4*)((isC ? p.icw : p.ihw) + (size_t)j*E_);
    float acc = 0.f;
    #pragma unroll 4
    for (int k4 = 0; k4 < 128; k4++) acc += dot4(x4[k4*64 + lane], w4[k4]);
    acc += (isC ? p.icb : p.ihb)[j];
    if (isC) p.cT[j*64 + lane] = acc;
    else {
      p.hb0[((j>>2)*64 + lane)*4 + (j&3)] = acc;
      p.hB[(size_t)lane*512 + j] = acc;
    }
  }
  gridbar(p.bar, blk);

  // ---------------- time loop ----------------
  for (int t = 0; t < T_; t++){
    const float* hT = (t & 1) ? p.hb1 : p.hb0;
    float*       hN = (t & 1) ? p.hb0 : p.hb1;

    // ======== Phase A ========
    // A0: preds(t-1) partial dots (all blocks; column v = blk*4 + (wave&3), K halved over wave>>2)
    if (t > 0){
      int v = blk*4 + (wave & 3);
      if (v < 1000){
        const float4* h4 = (const float4*)p.hnT;
        const float4* w4 = (const float4*)(p.fcw + (size_t)v*D_);
        int k0 = (wave>>2)*64;
        float a0 = 0.f, a1 = 0.f;
        for (int kk = 0; kk < 64; kk += 2){
          a0 += dot4(h4[(k0+kk  )*64 + lane], w4[k0+kk  ]);
          a1 += dot4(h4[(k0+kk+1)*64 + lane], w4[k0+kk+1]);
        }
        predP[wave*64 + lane] = a0 + a1;
      }
    }
    // A1: zero own awe quarter of xT; stage h[b]
    if (tid < 32){
      float4 z = make_float4(0.f,0.f,0.f,0.f);
      ((float4*)p.xT)[(128 + q*32 + tid)*64 + b] = z;
    }
    hL[tid] = p.hB[(size_t)b*512 + tid];
    __syncthreads();
    // A2: finish preds(t-1)
    if (t > 0 && wave < 4){
      int v = blk*4 + wave;
      if (v < 1000){
        float sum = predP[wave*64 + lane] + predP[(wave+4)*64 + lane] + p.fcb[v];
        bool mm = (t-1) < p.dec_len[lane];
        p.out[OUT_PRED + ((size_t)lane*T_ + (t-1))*V_ + v] = mm ? sum : 0.f;
      }
    }
    // A3: att2 + gate columns for own quarter (cols q*128 .. q*128+127)
    {
      const float4* hL4 = (const float4*)hL;
      float4 h0v = hL4[lane*2], h1v = hL4[lane*2+1];
      for (int cc = 0; cc < 16; cc++){
        int c = q*128 + wave*16 + cc;
        const float4* w4 = (const float4*)(p.daw + (size_t)c*D_);
        float4 wa = w4[lane*2], wb = w4[lane*2+1];
        float s = dot4(wa,h0v) + dot4(wb,h1v);
        #pragma unroll
        for (int o = 32; o > 0; o >>= 1) s += __shfl_down(s, o);
        if (lane == 0) p.a2B[b*512 + c] = s + p.dab[c];
        const float4* v4 = (const float4*)(p.fbw + (size_t)c*D_);
        float4 va = v4[lane*2], vb = v4[lane*2+1];
        float g = dot4(va,h0v) + dot4(vb,h1v);
        #pragma unroll
        for (int o = 32; o > 0; o >>= 1) g += __shfl_down(g, o);
        if (lane == 0) p.gateB[b*512 + c] = sigf(g + p.fbb[c]);
      }
    }
    groupbar(gs);
    // A4: e for own 49 rows, from LDS-resident att1 (bf16)
    a2L[tid] = p.a2B[b*512 + tid];
    __syncthreads();
    {
      float4 aA = ((float4*)a2L)[lane*2], aB = ((float4*)a2L)[lane*2+1];
      float4 fA = ((float4*)fwL)[lane*2], fB = ((float4*)fwL)[lane*2+1];
      float fab0 = p.fab[0];
      for (int pp = wave; pp < 49; pp += 8){
        uint4 raw = ((const uint4*)att1L)[pp*64 + lane];
        float s =
          fmaxf(__uint_as_float(raw.x << 16)        + aA.x, 0.f)*fA.x +
          fmaxf(__uint_as_float(raw.x & 0xffff0000u)+ aA.y, 0.f)*fA.y +
          fmaxf(__uint_as_float(raw.y << 16)        + aA.z, 0.f)*fA.z +
          fmaxf(__uint_as_float(raw.y & 0xffff0000u)+ aA.w, 0.f)*fA.w +
          fmaxf(__uint_as_float(raw.z << 16)        + aB.x, 0.f)*fB.x +
          fmaxf(__uint_as_float(raw.z & 0xffff0000u)+ aB.y, 0.f)*fB.y +
          fmaxf(__uint_as_float(raw.w << 16)        + aB.z, 0.f)*fB.z +
          fmaxf(__uint_as_float(raw.w & 0xffff0000u)+ aB.w, 0.f)*fB.w;
        #pragma unroll
        for (int o = 32; o > 0; o >>= 1) s += __shfl_down(s, o);
        if (lane == 0) p.eG[b*196 + q*49 + pp] = s + fab0;
      }
    }
    groupbar(gs);
    // A5: softmax over 196 (redundant x4 per group, deterministic), alpha out
    if (tid < 196) eL[tid] = p.eG[b*196 + tid];
    __syncthreads();
    if (wave == 0){
      float mx = -1e30f;
      for (int i = lane; i < P_; i += 64) mx = fmaxf(mx, eL[i]);
      #pragma unroll
      for (int o = 32; o > 0; o >>= 1) mx = fmaxf(mx, __shfl_xor(mx, o));
      float sum = 0.f;
      for (int i = lane; i < P_; i += 64){
        float ex = __expf(eL[i] - mx);
        alL[i] = ex;
        sum += ex;
      }
      #pragma unroll
      for (int o = 32; o > 0; o >>= 1) sum += __shfl_xor(sum, o);
      float inv = 1.f / sum;
      for (int i = lane; i < P_; i += 64) alL[i] *= inv;
    }
    __syncthreads();
    {
      bool mb = t < p.dec_len[b];
      if (tid < 49)
        p.out[OUT_ALPHA + ((size_t)b*T_ + t)*P_ + q*49 + tid] = mb ? alL[q*49 + tid] : 0.f;
    }
    // A6: partial awe * gate -> atomicAdd into xT (gate distributes over partial sums)
    {
      const int e = tid;
      float g = p.gateB[b*512 + e];
      const unsigned short* ecol = encL + e;
      float s0=0.f,s1=0.f,s2=0.f,s3=0.f;
      for (int pp = 0; pp < 48; pp += 4){
        s0 = fmaf(alL[q*49+pp+0], bf2f(ecol[(pp+0)*512]), s0);
        s1 = fmaf(alL[q*49+pp+1], bf2f(ecol[(pp+1)*512]), s1);
        s2 = fmaf(alL[q*49+pp+2], bf2f(ecol[(pp+2)*512]), s2);
        s3 = fmaf(alL[q*49+pp+3], bf2f(ecol[(pp+3)*512]), s3);
      }
      s0 = fmaf(alL[q*49+48], bf2f(ecol[48*512]), s0);
      float val = g * ((s0+s1)+(s2+s3));
      atomicAdd(&p.xT[(size_t)(128 + (e>>2))*256 + b*4 + (e&3)], val);
    }
    // A7: emb quarter into xT
    if (tid < 32){
      int cap = p.capT[t*B_ + b];
      float4 ev = *(const float4*)(p.emb + (size_t)cap*M_ + q*128 + tid*4);
      ((float4*)p.xT)[(q*32 + tid)*64 + b] = ev;
    }
    gridbar(p.bar, blk);

    // ======== Phase C: gates GEMM (K-split 4 waves) + LSTM pointwise ========
    {
      const int j  = blk*2 + (wave >> 2);
      const int kc = wave & 3;
      float ag[4] = {0.f,0.f,0.f,0.f};
      const float4* x4 = (const float4*)p.xT;
      const float4* h4 = (const float4*)hT;
      for (int kk = 0; kk < 384; kk += 4){
        int k = kc*384 + kk;
        if (k < 1024){
          float4 xv = x4[(k>>2)*64 + lane];
          #pragma unroll
          for (int g = 0; g < 4; g++){
            float4 wv = *(const float4*)(p.wih + (size_t)(j + 512*g)*1024 + k);
            ag[g] = fmaf(xv.x, wv.x, ag[g]); ag[g] = fmaf(xv.y, wv.y, ag[g]);
            ag[g] = fmaf(xv.z, wv.z, ag[g]); ag[g] = fmaf(xv.w, wv.w, ag[g]);
          }
        } else {
          int kh = k - 1024;
          float4 xv = h4[(kh>>2)*64 + lane];
          #pragma unroll
          for (int g = 0; g < 4; g++){
            float4 wv = *(const float4*)(p.whh + (size_t)(j + 512*g)*512 + kh);
            ag[g] = fmaf(xv.x, wv.x, ag[g]); ag[g] = fmaf(xv.y, wv.y, ag[g]);
            ag[g] = fmaf(xv.z, wv.z, ag[g]); ag[g] = fmaf(xv.w, wv.w, ag[g]);
          }
        }
      }
      float (*pa)[4][64] = (float (*)[4][64])part;
      #pragma unroll
      for (int g = 0; g < 4; g++) pa[wave][g][lane] = ag[g];
      __syncthreads();
      if ((wave & 3) == 0){
        const int wb = wave;
        float gsv[4];
        #pragma unroll
        for (int g = 0; g < 4; g++){
          gsv[g] = pa[wb][g][lane] + pa[wb+1][g][lane] + pa[wb+2][g][lane] + pa[wb+3][g][lane]
                 + p.bih[j + 512*g] + p.bhh[j + 512*g];
        }
        float c_old = p.cT[j*64 + lane];
        float i_s = sigf(gsv[0]);
        float f_s = sigf(gsv[1]);
        float g_t = tanhf_(gsv[2]);
        float o_s = sigf(gsv[3]);
        float c_new = f_s*c_old + i_s*g_t;
        float h_new = o_s*tanhf_(c_new);
        bool m = t < p.dec_len[lane];
        float h_old = hT[((j>>2)*64 + lane)*4 + (j&3)];
        float h2 = m ? h_new : h_old;
        float c2 = m ? c_new : c_old;
        p.cT[j*64 + lane] = c2;
        p.hnT[((j>>2)*64 + lane)*4 + (j&3)] = h_new;
        hN  [((j>>2)*64 + lane)*4 + (j&3)] = h2;
        p.hB[(size_t)lane*512 + j] = h2;
      }
    }
    gridbar(p.bar, blk);
  }

  // ---- final preds for t = T-1 ----
  {
    int v = blk*4 + (wave & 3);
    if (v < 1000){
      const float4* h4 = (const float4*)p.hnT;
      const float4* w4 = (const float4*)(p.fcw + (size_t)v*D_);
      int k0 = (wave>>2)*64;
      float a0 = 0.f, a1 = 0.f;
      for (int kk = 0; kk < 64; kk += 2){
        a0 += dot4(h4[(k0+kk  )*64 + lane], w4[k0+kk  ]);
        a1 += dot4(h4[(k0+kk+1)*64 + lane], w4[k0+kk+1]);
      }
      predP[wave*64 + lane] = a0 + a1;
    }
    __syncthreads();
    if (wave < 4){
      int v2 = blk*4 + wave;
      if (v2 < 1000){
        float sum = predP[wave*64 + lane] + predP[(wave+4)*64 + lane] + p.fcb[v2];
        bool mm = (T_-1) < p.dec_len[lane];
        p.out[OUT_PRED + ((size_t)lane*T_ + (T_-1))*V_ + v2] = mm ? sum : 0.f;
      }
    }
  }
}

extern "C" void kernel_launch(void* const* d_in, const int* in_sizes, int n_in,
                              void* d_out, int out_size, void* d_ws, size_t ws_size,
                              hipStream_t stream){
  (void)in_sizes; (void)n_in; (void)out_size; (void)ws_size;
  KP p;
  p.enc  = (const float*)d_in[0];
  p.caps = (const int*)  d_in[1];
  p.clen = (const int*)  d_in[2];
  p.emb  = (const float*)d_in[3];
  p.eaw  = (const float*)d_in[4];  p.eab = (const float*)d_in[5];
  p.daw  = (const float*)d_in[6];  p.dab = (const float*)d_in[7];
  p.faw  = (const float*)d_in[8];  p.fab = (const float*)d_in[9];
  p.wih  = (const float*)d_in[10]; p.bih = (const float*)d_in[11];
  p.whh  = (const float*)d_in[12]; p.bhh = (const float*)d_in[13];
  p.ihw  = (const float*)d_in[14]; p.ihb = (const float*)d_in[15];
  p.icw  = (const float*)d_in[16]; p.icb = (const float*)d_in[17];
  p.fbw  = (const float*)d_in[18]; p.fbb = (const float*)d_in[19];
  p.fcw  = (const float*)d_in[20]; p.fcb = (const float*)d_in[21];
  p.out  = (float*)d_out;

  char* ws = (char*)d_ws;
  size_t off = 0;
  p.bar      = (int*)(ws + off); off += 1024;             // tree barrier (leafs/root/sense)
  p.gsync    = (int*)(ws + off); off += 64*16*4;          // per-group sub-barriers
  p.sort_ind = (int*)(ws + off); off += 64*4;
  p.dec_len  = (int*)(ws + off); off += 64*4;
  p.capT     = (int*)(ws + off); off += (size_t)L_*B_*4;
  off = (off + 255) & ~(size_t)255;
  p.hb0   = (float*)(ws + off); off += (size_t)D_*B_*4;
  p.hb1   = (float*)(ws + off); off += (size_t)D_*B_*4;
  p.cT    = (float*)(ws + off); off += (size_t)D_*B_*4;
  p.hnT   = (float*)(ws + off); off += (size_t)D_*B_*4;
  p.a2B   = (float*)(ws + off); off += (size_t)B_*A_*4;
  p.gateB = (float*)(ws + off); off += (size_t)B_*E_*4;
  p.hB    = (float*)(ws + off); off += (size_t)B_*D_*4;
  p.xT    = (float*)(ws + off); off += (size_t)(M_+E_)*B_*4;
  p.mnT   = (float*)(ws + off); off += (size_t)E_*B_*4;
  p.eG    = (float*)(ws + off); off += (size_t)B_*P_*4;
  p.att1  = (float*)(ws + off); off += (size_t)B_*P_*A_*4;

  hipMemsetAsync(p.bar, 0, 1024 + 64*16*4, stream);

  void* args[] = { (void*)&p };
  hipLaunchCooperativeKernel((const void*)dec_kernel,
                             dim3(NBLK), dim3(NTHR), args, 0, stream);
}